// Round 7
// baseline (171.982 us; speedup 1.0000x reference)
//
#include <hip/hip_runtime.h>
#include <math.h>

// Burgers PINN: u = MLP(x,t) (2->10x7->1, tanh), outputs u, f, u_x, u_xx at 1M
// collocation points + plain forward at 3x16384 IC/boundary points.
// Forward-mode AD with 4 channels: (val, d/dx, d/dt, d2/dx2).
//
// R7: SEQUENTIAL channel matmuls (Zx then Zt then Zxx then Z) so each input
// vector (Hx/Ht/Hxx/H) dies before the next channel starts — peak live state
// drops ~80 -> ~55 regs, fitting under the allocator's arch-VGPR cap (which
// was forcing AGPR spill churn: VGPR_Count=52 vs ~136 unified regs/wave).
// op_sel asm broadcast kept from R6. __launch_bounds__(256,6): cap ~85 VGPR,
// occupancy target 6 waves/EU (R5/R6's waves_per_eu(3,4) max-capped at 3-4).

#define NU_CONST 0.0031830988618379067f   // 0.01 / pi
#define TWO_OVER_LN2 2.8853900817779268f  // 2 / ln(2)

typedef float v2f __attribute__((ext_vector_type(2)));

__device__ __forceinline__ v2f splat2(float s) {
    v2f r; r.x = s; r.y = s; return r;
}
__device__ __forceinline__ v2f pk_fma(v2f a, v2f b, v2f c) {
    return __builtin_elementwise_fma(a, b, c);
}

// acc(pair) += act.lo * w(pair): op_sel broadcasts src0's LOW half.
__device__ __forceinline__ void fma_blo(v2f& acc, v2f act, v2f w) {
    asm("v_pk_fma_f32 %0, %1, %2, %0 op_sel:[0,0,0] op_sel_hi:[0,1,1]"
        : "+v"(acc) : "v"(act), "s"(w));
}
// acc(pair) += act.hi * w(pair)
__device__ __forceinline__ void fma_bhi(v2f& acc, v2f act, v2f w) {
    asm("v_pk_fma_f32 %0, %1, %2, %0 op_sel:[1,0,0] op_sel_hi:[1,1,1]"
        : "+v"(acc) : "v"(act), "s"(w));
}
// dst(pair) = act.lo * w(pair)  (row-0 peel for derivative channels)
__device__ __forceinline__ v2f mul_blo(v2f act, v2f w) {
    v2f d;
    asm("v_pk_mul_f32 %0, %1, %2 op_sel:[0,0] op_sel_hi:[0,1]"
        : "=v"(d) : "v"(act), "s"(w));
    return d;
}

__device__ __forceinline__ float fast_tanh(float x) {
    float e = __builtin_amdgcn_exp2f(x * TWO_OVER_LN2);
    float r = __builtin_amdgcn_rcpf(e + 1.0f);
    return fmaf(-2.0f, r, 1.0f);
}

// Packed tanh on a pair.
__device__ __forceinline__ v2f tanh2(v2f z2) {
    v2f a2 = z2 * splat2(TWO_OVER_LN2);
    v2f e2;
    e2.x = __builtin_amdgcn_exp2f(a2.x);
    e2.y = __builtin_amdgcn_exp2f(a2.y);
    v2f ep = e2 + splat2(1.0f);
    v2f r2;
    r2.x = __builtin_amdgcn_rcpf(ep.x);
    r2.y = __builtin_amdgcn_rcpf(ep.y);
    return pk_fma(splat2(-2.0f), r2, splat2(1.0f));
}

// One 10-wide matmul channel: Acc[5](pairs) = act-channel^T * W (rows 0..9).
// Row 0 peeled as a mul (deriv channels have no bias).
__device__ __forceinline__ void chan_matmul(const float* __restrict__ W,
                                            const v2f A[5], v2f Acc[5]) {
#pragma unroll
    for (int jp = 0; jp < 5; ++jp)
        Acc[jp] = mul_blo(A[0], *(const v2f*)(W + 2 * jp));
#pragma unroll
    for (int i = 1; i < 10; ++i) {
        const int p = i >> 1;
#pragma unroll
        for (int jp = 0; jp < 5; ++jp) {
            v2f w2 = *(const v2f*)(W + i * 10 + 2 * jp);
            if (i & 1) fma_bhi(Acc[jp], A[p], w2);
            else       fma_blo(Acc[jp], A[p], w2);
        }
    }
}

// One hidden 10->10 tanh layer, 4 AD channels, SEQUENTIAL channel order so
// each input vector dies before the next channel's accumulators go live.
__device__ __forceinline__ void hidden10_ad_seq(const float* __restrict__ W,
                                                const float* __restrict__ B,
                                                v2f H[5], v2f Hx[5],
                                                v2f Ht[5], v2f Hxx[5]) {
    v2f Zx[5], Zt[5], Zxx[5], Z[5];
    chan_matmul(W, Hx, Zx);     // Hx dead after this
    chan_matmul(W, Ht, Zt);     // Ht dead
    chan_matmul(W, Hxx, Zxx);   // Hxx dead
    // Value channel last (needs bias); H dead after.
#pragma unroll
    for (int jp = 0; jp < 5; ++jp) {
        Z[jp] = *(const v2f*)(B + 2 * jp);   // SGPR->VGPR pair
        fma_blo(Z[jp], H[0], *(const v2f*)(W + 2 * jp));
    }
#pragma unroll
    for (int i = 1; i < 10; ++i) {
        const int p = i >> 1;
#pragma unroll
        for (int jp = 0; jp < 5; ++jp) {
            v2f w2 = *(const v2f*)(W + i * 10 + 2 * jp);
            if (i & 1) fma_bhi(Z[jp], H[p], w2);
            else       fma_blo(Z[jp], H[p], w2);
        }
    }
    // Nonlinear + chain, pairwise; Z* die as H* are rebuilt.
#pragma unroll
    for (int jp = 0; jp < 5; ++jp) {
        v2f v2v = tanh2(Z[jp]);
        v2f s2  = pk_fma(-v2v, v2v, splat2(1.0f));   // 1 - v^2
        v2f sx2 = s2 * Zx[jp];
        v2f m2v = splat2(-2.0f) * v2v;
        H[jp]   = v2v;
        Hx[jp]  = sx2;
        Ht[jp]  = s2 * Zt[jp];
        // d2/dx2 tanh(z) = s*zxx + (-2v)*(sx*zx)
        Hxx[jp] = pk_fma(s2, Zxx[jp], m2v * (sx2 * Zx[jp]));
    }
}

// Values-only hidden layer (boundary/IC points), packed over j-pairs.
__device__ __forceinline__ void hidden10_fwd(const float* __restrict__ W,
                                             const float* __restrict__ B,
                                             float h[10]) {
    v2f Z[5];
    {
        v2f hs = splat2(h[0]);
#pragma unroll
        for (int jp = 0; jp < 5; ++jp) {
            v2f w2 = *(const v2f*)(W + 2 * jp);
            v2f b2 = *(const v2f*)(B + 2 * jp);
            Z[jp] = pk_fma(hs, w2, b2);
        }
    }
#pragma unroll
    for (int i = 1; i < 10; ++i) {
        v2f hs = splat2(h[i]);
#pragma unroll
        for (int jp = 0; jp < 5; ++jp) {
            v2f w2 = *(const v2f*)(W + i * 10 + 2 * jp);
            Z[jp] = pk_fma(hs, w2, Z[jp]);
        }
    }
#pragma unroll
    for (int jp = 0; jp < 5; ++jp) {
        v2f v2v = tanh2(Z[jp]);
        h[2*jp] = v2v.x;
        h[2*jp+1] = v2v.y;
    }
}

__global__ __launch_bounds__(256, 6)
void pinn_fused_kernel(
    const float* __restrict__ Xf,
    const float* __restrict__ X0, const float* __restrict__ XL,
    const float* __restrict__ XR,
    const float* __restrict__ W1, const float* __restrict__ b1,
    const float* __restrict__ W2, const float* __restrict__ b2,
    const float* __restrict__ W3, const float* __restrict__ b3,
    const float* __restrict__ W4, const float* __restrict__ b4,
    const float* __restrict__ W5, const float* __restrict__ b5,
    const float* __restrict__ W6, const float* __restrict__ b6,
    const float* __restrict__ W7, const float* __restrict__ b7,
    const float* __restrict__ W8, const float* __restrict__ b8,
    const float* __restrict__ W9, const float* __restrict__ b9,
    float* __restrict__ out_u, float* __restrict__ out_f,
    float* __restrict__ out_ux, float* __restrict__ out_uxx,
    float* __restrict__ O0, float* __restrict__ OL, float* __restrict__ OR_,
    int n_colloc_blocks, int NF, int N0) {
    if ((int)blockIdx.x < n_colloc_blocks) {
        // ---------------- collocation path: 4 AD channels ----------------
        int idx = blockIdx.x * blockDim.x + threadIdx.x;
        if (idx >= NF) return;
        float2 xt = ((const float2*)Xf)[idx];
        float x = xt.x;
        float t = xt.y;

        v2f H[5], Hx[5], Ht[5], Hxx[5];
        // Layer 1: 2 -> 10, tanh. Seeds: dx=(1,0), dt=(0,1), dxx=0.
        {
            v2f xs = splat2(x);
            v2f ts = splat2(t);
#pragma unroll
            for (int jp = 0; jp < 5; ++jp) {
                v2f wx2 = *(const v2f*)(W1 + 2 * jp);        // W1 row 0
                v2f wt2 = *(const v2f*)(W1 + 10 + 2 * jp);   // W1 row 1
                v2f b2  = *(const v2f*)(b1 + 2 * jp);
                v2f z2  = pk_fma(xs, wx2, pk_fma(ts, wt2, b2));
                v2f v2v = tanh2(z2);
                v2f s2  = pk_fma(-v2v, v2v, splat2(1.0f));
                v2f sx2 = s2 * wx2;
                v2f m2v = splat2(-2.0f) * v2v;
                H[jp]   = v2v;
                Hx[jp]  = sx2;
                Ht[jp]  = s2 * wt2;
                Hxx[jp] = m2v * (sx2 * wx2);   // zxx = 0 at layer 1
            }
        }

        hidden10_ad_seq(W2, b2, H, Hx, Ht, Hxx);
        hidden10_ad_seq(W3, b3, H, Hx, Ht, Hxx);
        hidden10_ad_seq(W4, b4, H, Hx, Ht, Hxx);
        hidden10_ad_seq(W5, b5, H, Hx, Ht, Hxx);
        hidden10_ad_seq(W6, b6, H, Hx, Ht, Hxx);
        hidden10_ad_seq(W7, b7, H, Hx, Ht, Hxx);
        hidden10_ad_seq(W8, b8, H, Hx, Ht, Hxx);

        // Layer 9: 10 -> 1, linear. Pairwise dot then horizontal add.
        v2f u2, ux2, ut2, uxx2;
        {
            v2f w2 = *(const v2f*)(W9);
            u2   = H[0]   * w2;
            ux2  = Hx[0]  * w2;
            ut2  = Ht[0]  * w2;
            uxx2 = Hxx[0] * w2;
        }
#pragma unroll
        for (int jp = 1; jp < 5; ++jp) {
            v2f w2 = *(const v2f*)(W9 + 2 * jp);
            u2   = pk_fma(H[jp],   w2, u2);
            ux2  = pk_fma(Hx[jp],  w2, ux2);
            ut2  = pk_fma(Ht[jp],  w2, ut2);
            uxx2 = pk_fma(Hxx[jp], w2, uxx2);
        }
        float u   = b9[0] + (u2.x + u2.y);
        float ux  = ux2.x + ux2.y;
        float ut  = ut2.x + ut2.y;
        float uxx = uxx2.x + uxx2.y;

        out_u[idx]   = u;
        out_ux[idx]  = ux;
        out_uxx[idx] = uxx;
        out_f[idx]   = fmaf(u, ux, ut) - NU_CONST * uxx;  // u_t + u*u_x - nu*u_xx
    } else {
        // ---------------- forward-only path: IC + boundaries ----------------
        int idx = (blockIdx.x - n_colloc_blocks) * blockDim.x + threadIdx.x;
        if (idx >= 3 * N0) return;
        const float* X;
        float* O;
        int k;
        if (idx < N0)            { X = X0; O = O0;  k = idx; }
        else if (idx < 2 * N0)   { X = XL; O = OL;  k = idx - N0; }
        else                     { X = XR; O = OR_; k = idx - 2 * N0; }

        float2 xt = ((const float2*)X)[k];
        float x = xt.x;
        float t = xt.y;

        float h[10];
#pragma unroll
        for (int j = 0; j < 10; ++j) {
            float z = fmaf(x, W1[j], fmaf(t, W1[10 + j], b1[j]));
            h[j] = fast_tanh(z);
        }
        hidden10_fwd(W2, b2, h);
        hidden10_fwd(W3, b3, h);
        hidden10_fwd(W4, b4, h);
        hidden10_fwd(W5, b5, h);
        hidden10_fwd(W6, b6, h);
        hidden10_fwd(W7, b7, h);
        hidden10_fwd(W8, b8, h);

        float u = b9[0];
#pragma unroll
        for (int i = 0; i < 10; ++i) u = fmaf(h[i], W9[i], u);
        O[k] = u;
    }
}

extern "C" void kernel_launch(void* const* d_in, const int* in_sizes, int n_in,
                              void* d_out, int out_size, void* d_ws, size_t ws_size,
                              hipStream_t stream) {
    const float* Xf = (const float*)d_in[0];
    const float* X0 = (const float*)d_in[1];
    const float* XL = (const float*)d_in[2];
    const float* XR = (const float*)d_in[3];
    const float* W[9];
    const float* B[9];
    for (int i = 0; i < 9; ++i) {
        W[i] = (const float*)d_in[4 + 2 * i];
        B[i] = (const float*)d_in[5 + 2 * i];
    }
    int NF = in_sizes[0] / 2;
    int N0 = in_sizes[1] / 2;
    int NB = in_sizes[2] / 2;

    float* out = (float*)d_out;
    float* out_u   = out;                         // u_pred_f      [NF]
    float* out_0   = out + NF;                    // u_pred_0      [N0]
    float* out_bl  = out + NF + N0;               // u_pred_b_left [NB]
    float* out_br  = out + NF + N0 + NB;          // u_pred_b_right[NB]
    float* out_f   = out + NF + N0 + 2 * NB;      // f             [NF]
    float* out_ux  = out_f + NF;                  // u_x           [NF]
    float* out_uxx = out_ux + NF;                 // u_xx          [NF]

    int n_colloc_blocks = (NF + 255) / 256;
    int n_fwd_blocks    = (3 * N0 + 255) / 256;
    dim3 blk(256);
    dim3 grd(n_colloc_blocks + n_fwd_blocks);
    pinn_fused_kernel<<<grd, blk, 0, stream>>>(
        Xf, X0, XL, XR,
        W[0], B[0], W[1], B[1], W[2], B[2], W[3], B[3], W[4], B[4],
        W[5], B[5], W[6], B[6], W[7], B[7], W[8], B[8],
        out_u, out_f, out_ux, out_uxx,
        out_0, out_bl, out_br,
        n_colloc_blocks, NF, N0);
}